// Round 2
// baseline (5806.274 us; speedup 1.0000x reference)
//
#include <hip/hip_runtime.h>
#include <math.h>

#define DEV static __device__ __forceinline__

namespace {
constexpr int S  = 2048;   // seq len
constexpr int D  = 768;    // d_model
constexpr int Hh = 12;     // heads
constexpr int DK = 64;     // head dim
constexpr int F  = 3072;   // KAN hidden
constexpr int Nn = 4096;   // B*S tokens
}

// ---------------- LayerNorm: one block per row of 768 ---------------------
__global__ __launch_bounds__(256) void ln_kernel(const float* __restrict__ x,
                                                 const float* __restrict__ g,
                                                 const float* __restrict__ bta,
                                                 float* __restrict__ y) {
    int row = blockIdx.x;
    const float* xr = x + (size_t)row * D;
    float* yr = y + (size_t)row * D;
    int t = threadIdx.x;
    float v[3];
#pragma unroll
    for (int j = 0; j < 3; ++j) v[j] = xr[t + j * 256];
    float s = v[0] + v[1] + v[2];
#pragma unroll
    for (int o = 1; o < 64; o <<= 1) s += __shfl_xor(s, o, 64);
    __shared__ float red[4];
    __shared__ float red2[4];
    int wid = t >> 6;
    if ((t & 63) == 0) red[wid] = s;
    __syncthreads();
    float mean = (red[0] + red[1] + red[2] + red[3]) * (1.0f / 768.0f);
    float d0 = v[0] - mean, d1 = v[1] - mean, d2 = v[2] - mean;
    float sq = d0 * d0 + d1 * d1 + d2 * d2;
#pragma unroll
    for (int o = 1; o < 64; o <<= 1) sq += __shfl_xor(sq, o, 64);
    if ((t & 63) == 0) red2[wid] = sq;
    __syncthreads();
    float var = (red2[0] + red2[1] + red2[2] + red2[3]) * (1.0f / 768.0f);
    float rstd = rsqrtf(var + 1e-5f);
#pragma unroll
    for (int j = 0; j < 3; ++j) {
        int c = t + j * 256;
        yr[c] = (v[j] - mean) * rstd * g[c] + bta[c];
    }
}

// ---------------- QKV projection GEMM, writes (B,H,S,DK) ------------------
__global__ __launch_bounds__(256) void qkv_gemm(const float* __restrict__ A,
                                                const float* __restrict__ Wq,
                                                const float* __restrict__ Wk,
                                                const float* __restrict__ Wv,
                                                const float* __restrict__ bq,
                                                const float* __restrict__ bk,
                                                const float* __restrict__ bv,
                                                float* __restrict__ q,
                                                float* __restrict__ k,
                                                float* __restrict__ v) {
    int z = blockIdx.z;
    const float* W    = (z == 0) ? Wq : (z == 1) ? Wk : Wv;
    const float* bias = (z == 0) ? bq : (z == 1) ? bk : bv;
    float* out        = (z == 0) ? q  : (z == 1) ? k  : v;

    __shared__ float As[16][64];
    __shared__ float Bs[16][64];
    int t = threadIdx.x;
    int ty = t >> 4, tx = t & 15;
    int m0 = blockIdx.y * 64, o0 = blockIdx.x * 64;
    int lr = t >> 2, lch = t & 3;
    float acc[4][4] = {};
    for (int kt = 0; kt < D / 16; ++kt) {
        int k0 = kt * 16;
        if (kt) __syncthreads();
        float4 fa = *(const float4*)(A + (size_t)(m0 + lr) * D + k0 + lch * 4);
        As[lch * 4 + 0][lr] = fa.x;
        As[lch * 4 + 1][lr] = fa.y;
        As[lch * 4 + 2][lr] = fa.z;
        As[lch * 4 + 3][lr] = fa.w;
        float4 fb = *(const float4*)(W + (size_t)(o0 + lr) * D + k0 + lch * 4);
        Bs[lch * 4 + 0][lr] = fb.x;
        Bs[lch * 4 + 1][lr] = fb.y;
        Bs[lch * 4 + 2][lr] = fb.z;
        Bs[lch * 4 + 3][lr] = fb.w;
        __syncthreads();
#pragma unroll
        for (int kk = 0; kk < 16; ++kk) {
            float4 a4 = *(const float4*)&As[kk][ty * 4];
            float4 b4 = *(const float4*)&Bs[kk][tx * 4];
            float am[4] = {a4.x, a4.y, a4.z, a4.w};
            float bn[4] = {b4.x, b4.y, b4.z, b4.w};
#pragma unroll
            for (int m = 0; m < 4; ++m)
#pragma unroll
                for (int n = 0; n < 4; ++n)
                    acc[m][n] = fmaf(am[m], bn[n], acc[m][n]);
        }
    }
    int col0 = o0 + tx * 4;
    int hh = col0 >> 6, dd = col0 & 63;
#pragma unroll
    for (int m = 0; m < 4; ++m) {
        int n = m0 + ty * 4 + m;
        int b = n >> 11, ss = n & 2047;
        float4 rv;
        rv.x = acc[m][0] + bias[col0 + 0];
        rv.y = acc[m][1] + bias[col0 + 1];
        rv.z = acc[m][2] + bias[col0 + 2];
        rv.w = acc[m][3] + bias[col0 + 3];
        *(float4*)(out + (((size_t)(b * Hh + hh) * S + ss) * DK + dd)) = rv;
    }
}

// ---------------- Flash attention (fp32), 64 q-rows per block -------------
__global__ __launch_bounds__(256) void attn_kernel(const float* __restrict__ q,
                                                   const float* __restrict__ kg,
                                                   const float* __restrict__ vg,
                                                   float* __restrict__ outp) {
    int bh = blockIdx.y;            // 0..23
    int q0 = blockIdx.x * 64;
    int t = threadIdx.x;
    int r = t >> 2, dg = t & 3;     // row 0..63, dim-group 0..3 (16 dims each)

    __shared__ float Qs[64][65];
    __shared__ float KsT[64][64];   // [d][key]
    __shared__ float Vs[64][64];    // [key][d]
    __shared__ float Ps[64][65];

    const float* qb = q + ((size_t)bh * S + q0) * DK;
    const float* kb = kg + (size_t)bh * S * DK;
    const float* vb = vg + (size_t)bh * S * DK;

#pragma unroll
    for (int c4 = 0; c4 < 4; ++c4) {
        float4 f = *(const float4*)(qb + r * DK + dg * 16 + c4 * 4);
        Qs[r][dg * 16 + c4 * 4 + 0] = f.x;
        Qs[r][dg * 16 + c4 * 4 + 1] = f.y;
        Qs[r][dg * 16 + c4 * 4 + 2] = f.z;
        Qs[r][dg * 16 + c4 * 4 + 3] = f.w;
    }

    float acc[16];
#pragma unroll
    for (int j = 0; j < 16; ++j) acc[j] = 0.0f;
    float mrow = -INFINITY, lrow = 0.0f;

    for (int kt = 0; kt < S / 64; ++kt) {
        __syncthreads();  // prev PV done before restaging
#pragma unroll
        for (int c4 = 0; c4 < 4; ++c4) {
            float4 f = *(const float4*)(kb + ((size_t)kt * 64 + r) * DK + dg * 16 + c4 * 4);
            KsT[dg * 16 + c4 * 4 + 0][r] = f.x;
            KsT[dg * 16 + c4 * 4 + 1][r] = f.y;
            KsT[dg * 16 + c4 * 4 + 2][r] = f.z;
            KsT[dg * 16 + c4 * 4 + 3][r] = f.w;
            float4 g2 = *(const float4*)(vb + ((size_t)kt * 64 + r) * DK + dg * 16 + c4 * 4);
            *(float4*)&Vs[r][dg * 16 + c4 * 4] = g2;
        }
        __syncthreads();

        float sc[16];
#pragma unroll
        for (int j = 0; j < 16; ++j) sc[j] = 0.0f;
#pragma unroll 8
        for (int d = 0; d < 64; ++d) {
            float qv = Qs[r][d];
#pragma unroll
            for (int j4 = 0; j4 < 4; ++j4) {
                float4 kf = *(const float4*)&KsT[d][dg * 16 + j4 * 4];
                sc[j4 * 4 + 0] = fmaf(qv, kf.x, sc[j4 * 4 + 0]);
                sc[j4 * 4 + 1] = fmaf(qv, kf.y, sc[j4 * 4 + 1]);
                sc[j4 * 4 + 2] = fmaf(qv, kf.z, sc[j4 * 4 + 2]);
                sc[j4 * 4 + 3] = fmaf(qv, kf.w, sc[j4 * 4 + 3]);
            }
        }
        float pmax = -INFINITY;
#pragma unroll
        for (int j = 0; j < 16; ++j) {
            sc[j] *= 0.125f;
            pmax = fmaxf(pmax, sc[j]);
        }
        pmax = fmaxf(pmax, __shfl_xor(pmax, 1, 64));
        pmax = fmaxf(pmax, __shfl_xor(pmax, 2, 64));
        float mnew = fmaxf(mrow, pmax);
        float corr = __expf(mrow - mnew);   // first iter: exp(-inf)=0
        float p[16];
        float rs = 0.0f;
#pragma unroll
        for (int j = 0; j < 16; ++j) {
            p[j] = __expf(sc[j] - mnew);
            rs += p[j];
        }
        rs += __shfl_xor(rs, 1, 64);
        rs += __shfl_xor(rs, 2, 64);
        lrow = lrow * corr + rs;
        mrow = mnew;
#pragma unroll
        for (int j = 0; j < 16; ++j) acc[j] *= corr;
#pragma unroll
        for (int j = 0; j < 16; ++j) Ps[r][dg * 16 + j] = p[j];
        __syncthreads();
#pragma unroll 8
        for (int kk = 0; kk < 64; ++kk) {
            float pv = Ps[r][kk];
#pragma unroll
            for (int j4 = 0; j4 < 4; ++j4) {
                float4 vf = *(const float4*)&Vs[kk][dg * 16 + j4 * 4];
                acc[j4 * 4 + 0] = fmaf(pv, vf.x, acc[j4 * 4 + 0]);
                acc[j4 * 4 + 1] = fmaf(pv, vf.y, acc[j4 * 4 + 1]);
                acc[j4 * 4 + 2] = fmaf(pv, vf.z, acc[j4 * 4 + 2]);
                acc[j4 * 4 + 3] = fmaf(pv, vf.w, acc[j4 * 4 + 3]);
            }
        }
    }
    float inv = 1.0f / lrow;
    int b = bh / Hh, hh = bh % Hh;
    float* orow = outp + ((size_t)b * S + q0 + r) * D + hh * DK + dg * 16;
#pragma unroll
    for (int c4 = 0; c4 < 4; ++c4) {
        float4 rv;
        rv.x = acc[c4 * 4 + 0] * inv;
        rv.y = acc[c4 * 4 + 1] * inv;
        rv.z = acc[c4 * 4 + 2] * inv;
        rv.w = acc[c4 * 4 + 3] * inv;
        *(float4*)(orow + c4 * 4) = rv;
    }
}

// ---------------- elementwise residual add --------------------------------
__global__ __launch_bounds__(256) void add_kernel(const float* __restrict__ a,
                                                  const float* __restrict__ b,
                                                  float* __restrict__ o, int n4) {
    int i = blockIdx.x * 256 + threadIdx.x;
    if (i < n4) {
        float4 av = ((const float4*)a)[i];
        float4 bv = ((const float4*)b)[i];
        float4 ov;
        ov.x = av.x + bv.x; ov.y = av.y + bv.y;
        ov.z = av.z + bv.z; ov.w = av.w + bv.w;
        ((float4*)o)[i] = ov;
    }
}

// ------- KAN feature staging: silu + 4 nonzero cubic B-spline bases -------
// Uniform knots t[j] = (j-3)*0.4 - 1.0 (j=0..11). For x in [t[j], t[j+1]),
// u = (x - t[j]) / 0.4, the 4 nonzero degree-3 bases (of the 8 kept by the
// reference) are m = j-3..j with the standard uniform cubic blending polys.
template <int W>
DEV void stage_feat(float (&A)[72][W], int il, int lr, float xv) {
    float f0 = xv / (1.0f + __expf(-xv));   // silu (base feature)
    A[il * 9 + 0][lr] = f0;
#pragma unroll
    for (int c = 0; c < 8; ++c) A[il * 9 + 1 + c][lr] = 0.0f;
    float sp = (xv + 2.2f) * 2.5f;          // (x - t0)/h
    float fj = floorf(sp);
    int j = (int)fj;
    if (j >= 0 && j < 11) {
        float u = sp - fj;
        float u2 = u * u, u3 = u2 * u;
        float omu = 1.0f - u;
        float b0 = (1.0f / 6.0f) * omu * omu * omu;
        float b1 = 0.5f * u3 - u2 + (2.0f / 3.0f);
        float b2 = -0.5f * u3 + 0.5f * u2 + 0.5f * u + (1.0f / 6.0f);
        float b3 = (1.0f / 6.0f) * u3;
        if (j >= 3)           A[il * 9 + 1 + j - 3][lr] = b0;
        if (j >= 2 && j <= 9) A[il * 9 + 1 + j - 2][lr] = b1;
        if (j >= 1 && j <= 8) A[il * 9 + 1 + j - 1][lr] = b2;
        if (j <= 7)           A[il * 9 + 1 + j    ][lr] = b3;
    }
}

// ---------------- KAN linear: base(silu) + spline, fused GEMM -------------
// out[n,o] = sum_i silu(X[n,i])*bw[o,i] + sum_{i,c} B(X[n,i])_c * sw[o,i,c]*scal[o,i]
// Tile: BM x 64, BK=8 inputs -> 72 features per K-step. 256 threads,
// micro-tile MR x 4 (16x16 thread grid).
template <int IN, int BM, int MR>
__global__ __launch_bounds__(256) void kan_kernel(const float* __restrict__ X,
                                                  const float* __restrict__ bw,
                                                  const float* __restrict__ sw,
                                                  const float* __restrict__ scal,
                                                  const float* __restrict__ res,
                                                  float* __restrict__ out, int O) {
    __shared__ float As[72][BM];  // [feature][row]
    __shared__ float Bs[72][64];  // [feature][col]
    int t = threadIdx.x;
    int ty = t >> 4, tx = t & 15;
    int m0 = blockIdx.y * BM, o0 = blockIdx.x * 64;

    float acc[MR][4] = {};

    for (int kt = 0; kt < IN / 8; ++kt) {
        int i0 = kt * 8;
        if (kt) __syncthreads();   // previous FMA done before LDS overwrite
        // ---- stage A features ----
        if constexpr (BM == 128) {
            int lr = t >> 1, lch = (t & 1) * 4;
            float4 hv = *(const float4*)(X + (size_t)(m0 + lr) * IN + i0 + lch);
            stage_feat<BM>(As, lch + 0, lr, hv.x);
            stage_feat<BM>(As, lch + 1, lr, hv.y);
            stage_feat<BM>(As, lch + 2, lr, hv.z);
            stage_feat<BM>(As, lch + 3, lr, hv.w);
        } else {  // BM == 64
            int lr = t >> 2, lch = (t & 3) * 2;
            float2 hv = *(const float2*)(X + (size_t)(m0 + lr) * IN + i0 + lch);
            stage_feat<BM>(As, lch + 0, lr, hv.x);
            stage_feat<BM>(As, lch + 1, lr, hv.y);
        }
        // ---- stage B weights (2 inputs per thread) ----
        {
            int lo = t >> 2, lb = (t & 3) * 2;
            size_t base = (size_t)(o0 + lo) * IN + i0 + lb;
            float2 bwv = *(const float2*)(bw + base);
            float2 scv = *(const float2*)(scal + base);
#pragma unroll
            for (int ii = 0; ii < 2; ++ii) {
                int il = lb + ii;
                float sc = ii ? scv.y : scv.x;
                const float4* swp = (const float4*)(sw + (base + ii) * 8);
                float4 s0 = swp[0], s1 = swp[1];
                Bs[il * 9 + 0][lo] = ii ? bwv.y : bwv.x;
                Bs[il * 9 + 1][lo] = s0.x * sc;
                Bs[il * 9 + 2][lo] = s0.y * sc;
                Bs[il * 9 + 3][lo] = s0.z * sc;
                Bs[il * 9 + 4][lo] = s0.w * sc;
                Bs[il * 9 + 5][lo] = s1.x * sc;
                Bs[il * 9 + 6][lo] = s1.y * sc;
                Bs[il * 9 + 7][lo] = s1.z * sc;
                Bs[il * 9 + 8][lo] = s1.w * sc;
            }
        }
        __syncthreads();
#pragma unroll 8
        for (int kf = 0; kf < 72; ++kf) {
            float4 bv = *(const float4*)&Bs[kf][tx * 4];
            float bn[4] = {bv.x, bv.y, bv.z, bv.w};
            float am[MR];
            if constexpr (MR == 8) {
                float4 a0 = *(const float4*)&As[kf][ty * 8];
                float4 a1 = *(const float4*)&As[kf][ty * 8 + 4];
                am[0] = a0.x; am[1] = a0.y; am[2] = a0.z; am[3] = a0.w;
                am[4] = a1.x; am[5] = a1.y; am[6] = a1.z; am[7] = a1.w;
            } else {
                float4 a0 = *(const float4*)&As[kf][ty * 4];
                am[0] = a0.x; am[1] = a0.y; am[2] = a0.z; am[3] = a0.w;
            }
#pragma unroll
            for (int m = 0; m < MR; ++m)
#pragma unroll
                for (int n = 0; n < 4; ++n)
                    acc[m][n] = fmaf(am[m], bn[n], acc[m][n]);
        }
    }
#pragma unroll
    for (int m = 0; m < MR; ++m) {
        int row = m0 + ty * MR + m;
        size_t off = (size_t)row * O + o0 + tx * 4;
        float4 rv;
        rv.x = acc[m][0]; rv.y = acc[m][1];
        rv.z = acc[m][2]; rv.w = acc[m][3];
        if (res) {
            float4 rr = *(const float4*)(res + off);
            rv.x += rr.x; rv.y += rr.y; rv.z += rr.z; rv.w += rr.w;
        }
        *(float4*)(out + off) = rv;
    }
}

// ---------------- launcher -------------------------------------------------
extern "C" void kernel_launch(void* const* d_in, const int* in_sizes, int n_in,
                              void* d_out, int out_size, void* d_ws, size_t ws_size,
                              hipStream_t stream) {
    const float* x    = (const float*)d_in[0];
    // d_in[1] = mask (unused)
    const float* ln1g = (const float*)d_in[2];
    const float* ln1b = (const float*)d_in[3];
    const float* wq   = (const float*)d_in[4];
    const float* bq   = (const float*)d_in[5];
    const float* wk   = (const float*)d_in[6];
    const float* bk   = (const float*)d_in[7];
    const float* wv   = (const float*)d_in[8];
    const float* bv   = (const float*)d_in[9];
    const float* ln2g = (const float*)d_in[10];
    const float* ln2b = (const float*)d_in[11];
    const float* bw1  = (const float*)d_in[12];
    const float* sw1  = (const float*)d_in[13];
    const float* sc1  = (const float*)d_in[14];
    const float* bw2  = (const float*)d_in[15];
    const float* sw2  = (const float*)d_in[16];
    const float* sc2  = (const float*)d_in[17];

    float* ws   = (float*)d_ws;
    const size_t ND = (size_t)Nn * D;
    float* xn   = ws;            // LN1 out; later reused as attn output
    float* q    = xn + ND;       // Q; later reused as LN2 out (h)
    float* k    = q + ND;
    float* v    = k + ND;
    float* x1   = v + ND;
    float* h1   = x1 + ND;       // Nn * F

    // 1. LN1
    ln_kernel<<<Nn, 256, 0, stream>>>(x, ln1g, ln1b, xn);
    // 2. QKV projections (reads xn)
    qkv_gemm<<<dim3(D / 64, Nn / 64, 3), 256, 0, stream>>>(xn, wq, wk, wv, bq, bk, bv, q, k, v);
    // 3. attention -> reuse xn as output
    attn_kernel<<<dim3(S / 64, 2 * Hh), 256, 0, stream>>>(q, k, v, xn);
    // 4. residual: x1 = x + attn
    add_kernel<<<(int)(ND / 4 / 256), 256, 0, stream>>>(x, xn, x1, (int)(ND / 4));
    // 5. LN2 -> reuse q as h
    ln_kernel<<<Nn, 256, 0, stream>>>(x1, ln2g, ln2b, q);
    // 6. KAN layer 1: 768 -> 3072   (1536 blocks, 2/CU resident, 3 rounds)
    kan_kernel<768, 128, 8><<<dim3(F / 64, Nn / 128), 256, 0, stream>>>(q, bw1, sw1, sc1, nullptr, h1, F);
    // 7. KAN layer 2: 3072 -> 768, + residual x1  (768 blocks = 3/CU exact)
    kan_kernel<3072, 64, 4><<<dim3(D / 64, Nn / 64), 256, 0, stream>>>(h1, bw2, sw2, sc2, x1, (float*)d_out, D);
}

// Round 3
// 3501.102 us; speedup vs baseline: 1.6584x; 1.6584x over previous
//
#include <hip/hip_runtime.h>
#include <hip/hip_fp16.h>
#include <math.h>

#define DEV static __device__ __forceinline__

namespace {
constexpr int S  = 2048;   // seq len
constexpr int D  = 768;    // d_model
constexpr int Hh = 12;     // heads
constexpr int DK = 64;     // head dim
constexpr int F  = 3072;   // KAN hidden
constexpr int Nn = 4096;   // B*S tokens
constexpr int FEAT = 10;   // 1 silu + 8 spline + 1 zero pad (K-alignment)
constexpr int IK = 16;     // inputs per K-step
constexpr int BK = IK * FEAT;      // 160 features per K-step
constexpr int LDA = BK + 8;        // 168 halves: stride 84 words, 84%32=20 -> 2-way free
}

typedef _Float16 half8 __attribute__((ext_vector_type(8)));
typedef _Float16 half2t __attribute__((ext_vector_type(2)));
typedef float f32x4 __attribute__((ext_vector_type(4)));

// ---------------- LayerNorm: one block per row of 768 ---------------------
__global__ __launch_bounds__(256) void ln_kernel(const float* __restrict__ x,
                                                 const float* __restrict__ g,
                                                 const float* __restrict__ bta,
                                                 float* __restrict__ y) {
    int row = blockIdx.x;
    const float* xr = x + (size_t)row * D;
    float* yr = y + (size_t)row * D;
    int t = threadIdx.x;
    float v[3];
#pragma unroll
    for (int j = 0; j < 3; ++j) v[j] = xr[t + j * 256];
    float s = v[0] + v[1] + v[2];
#pragma unroll
    for (int o = 1; o < 64; o <<= 1) s += __shfl_xor(s, o, 64);
    __shared__ float red[4];
    __shared__ float red2[4];
    int wid = t >> 6;
    if ((t & 63) == 0) red[wid] = s;
    __syncthreads();
    float mean = (red[0] + red[1] + red[2] + red[3]) * (1.0f / 768.0f);
    float d0 = v[0] - mean, d1 = v[1] - mean, d2 = v[2] - mean;
    float sq = d0 * d0 + d1 * d1 + d2 * d2;
#pragma unroll
    for (int o = 1; o < 64; o <<= 1) sq += __shfl_xor(sq, o, 64);
    if ((t & 63) == 0) red2[wid] = sq;
    __syncthreads();
    float var = (red2[0] + red2[1] + red2[2] + red2[3]) * (1.0f / 768.0f);
    float rstd = rsqrtf(var + 1e-5f);
#pragma unroll
    for (int j = 0; j < 3; ++j) {
        int c = t + j * 256;
        yr[c] = (v[j] - mean) * rstd * g[c] + bta[c];
    }
}

// LayerNorm of (xa + xb) — fuses the attention residual add
__global__ __launch_bounds__(256) void ln_sum_kernel(const float* __restrict__ xa,
                                                     const float* __restrict__ xb,
                                                     const float* __restrict__ g,
                                                     const float* __restrict__ bta,
                                                     float* __restrict__ y) {
    int row = blockIdx.x;
    const float* xar = xa + (size_t)row * D;
    const float* xbr = xb + (size_t)row * D;
    float* yr = y + (size_t)row * D;
    int t = threadIdx.x;
    float v[3];
#pragma unroll
    for (int j = 0; j < 3; ++j) v[j] = xar[t + j * 256] + xbr[t + j * 256];
    float s = v[0] + v[1] + v[2];
#pragma unroll
    for (int o = 1; o < 64; o <<= 1) s += __shfl_xor(s, o, 64);
    __shared__ float red[4];
    __shared__ float red2[4];
    int wid = t >> 6;
    if ((t & 63) == 0) red[wid] = s;
    __syncthreads();
    float mean = (red[0] + red[1] + red[2] + red[3]) * (1.0f / 768.0f);
    float d0 = v[0] - mean, d1 = v[1] - mean, d2 = v[2] - mean;
    float sq = d0 * d0 + d1 * d1 + d2 * d2;
#pragma unroll
    for (int o = 1; o < 64; o <<= 1) sq += __shfl_xor(sq, o, 64);
    if ((t & 63) == 0) red2[wid] = sq;
    __syncthreads();
    float var = (red2[0] + red2[1] + red2[2] + red2[3]) * (1.0f / 768.0f);
    float rstd = rsqrtf(var + 1e-5f);
#pragma unroll
    for (int j = 0; j < 3; ++j) {
        int c = t + j * 256;
        yr[c] = (v[j] - mean) * rstd * g[c] + bta[c];
    }
}

// ---------------- QKV projection GEMM, writes (B,H,S,DK) ------------------
__global__ __launch_bounds__(256) void qkv_gemm(const float* __restrict__ A,
                                                const float* __restrict__ Wq,
                                                const float* __restrict__ Wk,
                                                const float* __restrict__ Wv,
                                                const float* __restrict__ bq,
                                                const float* __restrict__ bk,
                                                const float* __restrict__ bv,
                                                float* __restrict__ q,
                                                float* __restrict__ k,
                                                float* __restrict__ v) {
    int z = blockIdx.z;
    const float* W    = (z == 0) ? Wq : (z == 1) ? Wk : Wv;
    const float* bias = (z == 0) ? bq : (z == 1) ? bk : bv;
    float* out        = (z == 0) ? q  : (z == 1) ? k  : v;

    __shared__ float As[16][64];
    __shared__ float Bs[16][64];
    int t = threadIdx.x;
    int ty = t >> 4, tx = t & 15;
    int m0 = blockIdx.y * 64, o0 = blockIdx.x * 64;
    int lr = t >> 2, lch = t & 3;
    float acc[4][4] = {};
    for (int kt = 0; kt < D / 16; ++kt) {
        int k0 = kt * 16;
        if (kt) __syncthreads();
        float4 fa = *(const float4*)(A + (size_t)(m0 + lr) * D + k0 + lch * 4);
        As[lch * 4 + 0][lr] = fa.x;
        As[lch * 4 + 1][lr] = fa.y;
        As[lch * 4 + 2][lr] = fa.z;
        As[lch * 4 + 3][lr] = fa.w;
        float4 fb = *(const float4*)(W + (size_t)(o0 + lr) * D + k0 + lch * 4);
        Bs[lch * 4 + 0][lr] = fb.x;
        Bs[lch * 4 + 1][lr] = fb.y;
        Bs[lch * 4 + 2][lr] = fb.z;
        Bs[lch * 4 + 3][lr] = fb.w;
        __syncthreads();
#pragma unroll
        for (int kk = 0; kk < 16; ++kk) {
            float4 a4 = *(const float4*)&As[kk][ty * 4];
            float4 b4 = *(const float4*)&Bs[kk][tx * 4];
            float am[4] = {a4.x, a4.y, a4.z, a4.w};
            float bn[4] = {b4.x, b4.y, b4.z, b4.w};
#pragma unroll
            for (int m = 0; m < 4; ++m)
#pragma unroll
                for (int n = 0; n < 4; ++n)
                    acc[m][n] = fmaf(am[m], bn[n], acc[m][n]);
        }
    }
    int col0 = o0 + tx * 4;
    int hh = col0 >> 6, dd = col0 & 63;
#pragma unroll
    for (int m = 0; m < 4; ++m) {
        int n = m0 + ty * 4 + m;
        int b = n >> 11, ss = n & 2047;
        float4 rv;
        rv.x = acc[m][0] + bias[col0 + 0];
        rv.y = acc[m][1] + bias[col0 + 1];
        rv.z = acc[m][2] + bias[col0 + 2];
        rv.w = acc[m][3] + bias[col0 + 3];
        *(float4*)(out + (((size_t)(b * Hh + hh) * S + ss) * DK + dd)) = rv;
    }
}

// ---------------- Flash attention (fp32), 64 q-rows per block -------------
__global__ __launch_bounds__(256) void attn_kernel(const float* __restrict__ q,
                                                   const float* __restrict__ kg,
                                                   const float* __restrict__ vg,
                                                   float* __restrict__ outp) {
    int bh = blockIdx.y;            // 0..23
    int q0 = blockIdx.x * 64;
    int t = threadIdx.x;
    int r = t >> 2, dg = t & 3;     // row 0..63, dim-group 0..3 (16 dims each)

    __shared__ float Qs[64][65];
    __shared__ float KsT[64][64];   // [d][key]
    __shared__ float Vs[64][64];    // [key][d]
    __shared__ float Ps[64][65];

    const float* qb = q + ((size_t)bh * S + q0) * DK;
    const float* kb = kg + (size_t)bh * S * DK;
    const float* vb = vg + (size_t)bh * S * DK;

#pragma unroll
    for (int c4 = 0; c4 < 4; ++c4) {
        float4 f = *(const float4*)(qb + r * DK + dg * 16 + c4 * 4);
        Qs[r][dg * 16 + c4 * 4 + 0] = f.x;
        Qs[r][dg * 16 + c4 * 4 + 1] = f.y;
        Qs[r][dg * 16 + c4 * 4 + 2] = f.z;
        Qs[r][dg * 16 + c4 * 4 + 3] = f.w;
    }

    float acc[16];
#pragma unroll
    for (int j = 0; j < 16; ++j) acc[j] = 0.0f;
    float mrow = -INFINITY, lrow = 0.0f;

    for (int kt = 0; kt < S / 64; ++kt) {
        __syncthreads();
#pragma unroll
        for (int c4 = 0; c4 < 4; ++c4) {
            float4 f = *(const float4*)(kb + ((size_t)kt * 64 + r) * DK + dg * 16 + c4 * 4);
            KsT[dg * 16 + c4 * 4 + 0][r] = f.x;
            KsT[dg * 16 + c4 * 4 + 1][r] = f.y;
            KsT[dg * 16 + c4 * 4 + 2][r] = f.z;
            KsT[dg * 16 + c4 * 4 + 3][r] = f.w;
            float4 g2 = *(const float4*)(vb + ((size_t)kt * 64 + r) * DK + dg * 16 + c4 * 4);
            *(float4*)&Vs[r][dg * 16 + c4 * 4] = g2;
        }
        __syncthreads();

        float sc[16];
#pragma unroll
        for (int j = 0; j < 16; ++j) sc[j] = 0.0f;
#pragma unroll 8
        for (int d = 0; d < 64; ++d) {
            float qv = Qs[r][d];
#pragma unroll
            for (int j4 = 0; j4 < 4; ++j4) {
                float4 kf = *(const float4*)&KsT[d][dg * 16 + j4 * 4];
                sc[j4 * 4 + 0] = fmaf(qv, kf.x, sc[j4 * 4 + 0]);
                sc[j4 * 4 + 1] = fmaf(qv, kf.y, sc[j4 * 4 + 1]);
                sc[j4 * 4 + 2] = fmaf(qv, kf.z, sc[j4 * 4 + 2]);
                sc[j4 * 4 + 3] = fmaf(qv, kf.w, sc[j4 * 4 + 3]);
            }
        }
        float pmax = -INFINITY;
#pragma unroll
        for (int j = 0; j < 16; ++j) {
            sc[j] *= 0.125f;
            pmax = fmaxf(pmax, sc[j]);
        }
        pmax = fmaxf(pmax, __shfl_xor(pmax, 1, 64));
        pmax = fmaxf(pmax, __shfl_xor(pmax, 2, 64));
        float mnew = fmaxf(mrow, pmax);
        float corr = __expf(mrow - mnew);
        float p[16];
        float rs = 0.0f;
#pragma unroll
        for (int j = 0; j < 16; ++j) {
            p[j] = __expf(sc[j] - mnew);
            rs += p[j];
        }
        rs += __shfl_xor(rs, 1, 64);
        rs += __shfl_xor(rs, 2, 64);
        lrow = lrow * corr + rs;
        mrow = mnew;
#pragma unroll
        for (int j = 0; j < 16; ++j) acc[j] *= corr;
#pragma unroll
        for (int j = 0; j < 16; ++j) Ps[r][dg * 16 + j] = p[j];
        __syncthreads();
#pragma unroll 8
        for (int kk = 0; kk < 64; ++kk) {
            float pv = Ps[r][kk];
#pragma unroll
            for (int j4 = 0; j4 < 4; ++j4) {
                float4 vf = *(const float4*)&Vs[kk][dg * 16 + j4 * 4];
                acc[j4 * 4 + 0] = fmaf(pv, vf.x, acc[j4 * 4 + 0]);
                acc[j4 * 4 + 1] = fmaf(pv, vf.y, acc[j4 * 4 + 1]);
                acc[j4 * 4 + 2] = fmaf(pv, vf.z, acc[j4 * 4 + 2]);
                acc[j4 * 4 + 3] = fmaf(pv, vf.w, acc[j4 * 4 + 3]);
            }
        }
    }
    float inv = 1.0f / lrow;
    int b = bh / Hh, hh = bh % Hh;
    float* orow = outp + ((size_t)b * S + q0 + r) * D + hh * DK + dg * 16;
#pragma unroll
    for (int c4 = 0; c4 < 4; ++c4) {
        float4 rv;
        rv.x = acc[c4 * 4 + 0] * inv;
        rv.y = acc[c4 * 4 + 1] * inv;
        rv.z = acc[c4 * 4 + 2] * inv;
        rv.w = acc[c4 * 4 + 3] * inv;
        *(float4*)(orow + c4 * 4) = rv;
    }
}

// ------- KAN weight prep: fuse scaler, pad to 10 features, fp16 -----------
// Wp[o][i*10 + c] : c=0 -> base_w; c=1..8 -> spline_w[c-1]*scaler; c=9 -> 0
__global__ __launch_bounds__(256) void prep_kernel(const float* __restrict__ bw,
                                                   const float* __restrict__ sw,
                                                   const float* __restrict__ scal,
                                                   _Float16* __restrict__ Wp,
                                                   int total) {
    int idx = blockIdx.x * 256 + threadIdx.x;
    if (idx >= total) return;
    float bwv = bw[idx];
    float sc  = scal[idx];
    float4 s0 = *(const float4*)(sw + (size_t)idx * 8);
    float4 s1 = *(const float4*)(sw + (size_t)idx * 8 + 4);
    half2t p0 = {(_Float16)bwv,        (_Float16)(s0.x * sc)};
    half2t p1 = {(_Float16)(s0.y * sc), (_Float16)(s0.z * sc)};
    half2t p2 = {(_Float16)(s0.w * sc), (_Float16)(s1.x * sc)};
    half2t p3 = {(_Float16)(s1.y * sc), (_Float16)(s1.z * sc)};
    half2t p4 = {(_Float16)(s1.w * sc), (_Float16)0.0f};
    _Float16* dst = Wp + (size_t)idx * FEAT;
    *(half2t*)(dst + 0) = p0;
    *(half2t*)(dst + 2) = p1;
    *(half2t*)(dst + 4) = p2;
    *(half2t*)(dst + 6) = p3;
    *(half2t*)(dst + 8) = p4;
}

// ------- feature eval: silu + 8 cubic B-spline bases (static-indexed) -----
DEV void features10(float xv, float* f) {
    f[0] = xv / (1.0f + __expf(-xv));   // silu
    float sp = (xv + 2.2f) * 2.5f;      // (x - t0)/h
    float fj = floorf(sp);
    int j = (int)fj;                    // interval index; bases m=j-3..j nonzero
    float u = sp - fj;
    float u2 = u * u, u3 = u2 * u;
    float omu = 1.0f - u;
    float b0 = (1.0f / 6.0f) * omu * omu * omu;
    float b1 = 0.5f * u3 - u2 + (2.0f / 3.0f);
    float b2 = -0.5f * u3 + 0.5f * u2 + 0.5f * u + (1.0f / 6.0f);
    float b3 = (1.0f / 6.0f) * u3;
#pragma unroll
    for (int m = 0; m < 8; ++m) {
        int d = j - m;                  // static per-slot select (no dyn indexing)
        f[1 + m] = (d == 3) ? b0 : (d == 2) ? b1 : (d == 1) ? b2 : (d == 0) ? b3 : 0.0f;
    }
    f[9] = 0.0f;
}

template <typename T> DEV void load4(const T* p, float* x);
template <> DEV void load4<float>(const float* p, float* x) {
    float4 v = *(const float4*)p;
    x[0] = v.x; x[1] = v.y; x[2] = v.z; x[3] = v.w;
}
template <> DEV void load4<_Float16>(const _Float16* p, float* x) {
    half2t a = *(const half2t*)p;
    half2t b = *(const half2t*)(p + 2);
    x[0] = (float)a.x; x[1] = (float)a.y; x[2] = (float)b.x; x[3] = (float)b.y;
}

// ---------------- KAN linear via fp16 MFMA --------------------------------
// 64x64 tile, 4 waves of 32x32 (2x2 16x16 frags), K-step = 16 inputs = 160 feat.
template <int IN, typename InT, typename OutT, bool RES>
__global__ __launch_bounds__(256, 3) void kan16_kernel(const InT* __restrict__ X,
                                                       const _Float16* __restrict__ Wp,
                                                       const float* __restrict__ resA,
                                                       const float* __restrict__ resB,
                                                       OutT* __restrict__ out, int O) {
    __shared__ __align__(16) _Float16 As[64][LDA];
    __shared__ __align__(16) _Float16 Bs[64][LDA];
    int t = threadIdx.x;
    int l = t & 63, w = t >> 6;
    int m0 = blockIdx.y * 64, o0 = blockIdx.x * 64;
    int wr = (w >> 1) * 32, wc = (w & 1) * 32;
    int lm = l & 15, lk = (l >> 4) * 8;

    // staging roles
    int sm = t & 63, siq = t >> 6;      // A: row sm, inputs siq*4..+3
    int sn = t & 63, sq4 = t >> 6;      // B: row sn, 5 chunks of 8 halves

    f32x4 acc[2][2];
#pragma unroll
    for (int a = 0; a < 2; ++a)
#pragma unroll
        for (int b = 0; b < 2; ++b)
#pragma unroll
            for (int c = 0; c < 4; ++c) acc[a][b][c] = 0.0f;

    for (int kt = 0; kt < IN / IK; ++kt) {
        if (kt) __syncthreads();
        // ---- stage A: compute 10 features for 4 inputs of one row ----
        {
            float xv[4];
            load4<InT>(X + (size_t)(m0 + sm) * IN + kt * IK + siq * 4, xv);
#pragma unroll
            for (int jx = 0; jx < 4; ++jx) {
                float f[10];
                features10(xv[jx], f);
                int il = siq * 4 + jx;
#pragma unroll
                for (int p = 0; p < 5; ++p) {
                    half2t pv = {(_Float16)f[2 * p], (_Float16)f[2 * p + 1]};
                    *(half2t*)&As[sm][il * FEAT + p * 2] = pv;
                }
            }
        }
        // ---- stage B: copy 160 fp16 weights per row ----
        {
            const half8* src = (const half8*)(Wp + (size_t)(o0 + sn) * ((size_t)IN * FEAT)
                                              + (size_t)kt * BK + sq4 * 40);
#pragma unroll
            for (int cc = 0; cc < 5; ++cc) {
                half8 w8 = src[cc];
                *(half8*)&Bs[sn][sq4 * 40 + cc * 8] = w8;
            }
        }
        __syncthreads();
        // ---- inner: 5 K-chunks of 32, 4 MFMA each ----
#pragma unroll
        for (int kc = 0; kc < 5; ++kc) {
            half8 a0 = *(const half8*)&As[wr + lm][kc * 32 + lk];
            half8 a1 = *(const half8*)&As[wr + 16 + lm][kc * 32 + lk];
            half8 b0 = *(const half8*)&Bs[wc + lm][kc * 32 + lk];
            half8 b1 = *(const half8*)&Bs[wc + 16 + lm][kc * 32 + lk];
            acc[0][0] = __builtin_amdgcn_mfma_f32_16x16x32_f16(a0, b0, acc[0][0], 0, 0, 0);
            acc[0][1] = __builtin_amdgcn_mfma_f32_16x16x32_f16(a0, b1, acc[0][1], 0, 0, 0);
            acc[1][0] = __builtin_amdgcn_mfma_f32_16x16x32_f16(a1, b0, acc[1][0], 0, 0, 0);
            acc[1][1] = __builtin_amdgcn_mfma_f32_16x16x32_f16(a1, b1, acc[1][1], 0, 0, 0);
        }
    }
    // ---- epilogue: C/D frag map col=lane&15, row=(lane>>4)*4+reg ----
    int r0 = m0 + wr + (l >> 4) * 4;
    int c0 = o0 + wc + lm;
#pragma unroll
    for (int mf = 0; mf < 2; ++mf)
#pragma unroll
        for (int nf = 0; nf < 2; ++nf)
#pragma unroll
            for (int r = 0; r < 4; ++r) {
                int row = r0 + mf * 16 + r;
                int col = c0 + nf * 16;
                size_t off = (size_t)row * O + col;
                float vv = acc[mf][nf][r];
                if constexpr (RES) vv += resA[off] + resB[off];
                out[off] = (OutT)vv;
            }
}

// ---------------- launcher -------------------------------------------------
extern "C" void kernel_launch(void* const* d_in, const int* in_sizes, int n_in,
                              void* d_out, int out_size, void* d_ws, size_t ws_size,
                              hipStream_t stream) {
    const float* x    = (const float*)d_in[0];
    // d_in[1] = mask (unused)
    const float* ln1g = (const float*)d_in[2];
    const float* ln1b = (const float*)d_in[3];
    const float* wq   = (const float*)d_in[4];
    const float* bq   = (const float*)d_in[5];
    const float* wk   = (const float*)d_in[6];
    const float* bk   = (const float*)d_in[7];
    const float* wv   = (const float*)d_in[8];
    const float* bv   = (const float*)d_in[9];
    const float* ln2g = (const float*)d_in[10];
    const float* ln2b = (const float*)d_in[11];
    const float* bw1  = (const float*)d_in[12];
    const float* sw1  = (const float*)d_in[13];
    const float* sc1  = (const float*)d_in[14];
    const float* bw2  = (const float*)d_in[15];
    const float* sw2  = (const float*)d_in[16];
    const float* sc2  = (const float*)d_in[17];

    float* ws = (float*)d_ws;
    const size_t ND = (size_t)Nn * D;
    float* xn = ws;                     // LN1 out -> attn out (live to end)
    float* q  = ws + ND;                // Q -> h (LN2 out)
    float* k  = ws + 2 * ND;
    float* v  = ws + 3 * ND;
    _Float16* h1h = (_Float16*)(ws + 4 * ND);        // Nn*F fp16
    _Float16* Wp  = h1h + (size_t)Nn * F;            // shared weight buffer (47.2 MB)

    // 1. LN1
    ln_kernel<<<Nn, 256, 0, stream>>>(x, ln1g, ln1b, xn);
    // 2. QKV projections
    qkv_gemm<<<dim3(D / 64, Nn / 64, 3), 256, 0, stream>>>(xn, wq, wk, wv, bq, bk, bv, q, k, v);
    // 3. attention -> xn
    attn_kernel<<<dim3(S / 64, 2 * Hh), 256, 0, stream>>>(q, k, v, xn);
    // 4. LN2 of (x + attn) -> q  (residual add fused)
    ln_sum_kernel<<<Nn, 256, 0, stream>>>(x, xn, ln2g, ln2b, q);
    // 5. prep weights layer 1 (F x D)
    prep_kernel<<<(F * D + 255) / 256, 256, 0, stream>>>(bw1, sw1, sc1, Wp, F * D);
    // 6. KAN layer 1: 768 -> 3072, fp16 out
    kan16_kernel<768, float, _Float16, false>
        <<<dim3(F / 64, Nn / 64), 256, 0, stream>>>(q, Wp, nullptr, nullptr, h1h, F);
    // 7. prep weights layer 2 (D x F)
    prep_kernel<<<(D * F + 255) / 256, 256, 0, stream>>>(bw2, sw2, sc2, Wp, D * F);
    // 8. KAN layer 2: 3072 -> 768, + x + attn residuals, fp32 out
    kan16_kernel<3072, _Float16, float, true>
        <<<dim3(D / 64, Nn / 64), 256, 0, stream>>>(h1h, Wp, x, xn, (float*)d_out, D);
}

// Round 4
// 2227.394 us; speedup vs baseline: 2.6068x; 1.5718x over previous
//
#include <hip/hip_runtime.h>
#include <hip/hip_fp16.h>
#include <math.h>

#define DEV static __device__ __forceinline__

namespace {
constexpr int S  = 2048;
constexpr int D  = 768;
constexpr int Hh = 12;
constexpr int DK = 64;
constexpr int F  = 3072;
constexpr int Nn = 4096;
constexpr int FEAT = 10;       // 1 silu + 8 spline + 1 pad
constexpr int IK   = 16;       // inputs per K-step
constexpr int BKH  = IK * FEAT;   // 160 halves per K-step
constexpr int LDF  = 168;         // LDS row stride (halves); conflict-free (see notes)
}

typedef _Float16 half8 __attribute__((ext_vector_type(8)));
typedef _Float16 half2t __attribute__((ext_vector_type(2)));
typedef float f32x4 __attribute__((ext_vector_type(4)));

// ---------------- LN1: fp32 in -> fp16 out --------------------------------
__global__ __launch_bounds__(256) void ln16_kernel(const float* __restrict__ x,
                                                   const float* __restrict__ g,
                                                   const float* __restrict__ bta,
                                                   _Float16* __restrict__ y) {
    int row = blockIdx.x;
    const float* xr = x + (size_t)row * D;
    _Float16* yr = y + (size_t)row * D;
    int t = threadIdx.x;
    float v[3];
#pragma unroll
    for (int j = 0; j < 3; ++j) v[j] = xr[t + j * 256];
    float s = v[0] + v[1] + v[2];
#pragma unroll
    for (int o = 1; o < 64; o <<= 1) s += __shfl_xor(s, o, 64);
    __shared__ float red[4], red2[4];
    int wid = t >> 6;
    if ((t & 63) == 0) red[wid] = s;
    __syncthreads();
    float mean = (red[0] + red[1] + red[2] + red[3]) * (1.0f / 768.0f);
    float d0 = v[0] - mean, d1 = v[1] - mean, d2 = v[2] - mean;
    float sq = d0 * d0 + d1 * d1 + d2 * d2;
#pragma unroll
    for (int o = 1; o < 64; o <<= 1) sq += __shfl_xor(sq, o, 64);
    if ((t & 63) == 0) red2[wid] = sq;
    __syncthreads();
    float var = (red2[0] + red2[1] + red2[2] + red2[3]) * (1.0f / 768.0f);
    float rstd = rsqrtf(var + 1e-5f);
#pragma unroll
    for (int j = 0; j < 3; ++j) {
        int c = t + j * 256;
        yr[c] = (_Float16)((v[j] - mean) * rstd * g[c] + bta[c]);
    }
}

// ---------------- LN2 of (xa+xb): fp32 out --------------------------------
__global__ __launch_bounds__(256) void ln_sum_kernel(const float* __restrict__ xa,
                                                     const float* __restrict__ xb,
                                                     const float* __restrict__ g,
                                                     const float* __restrict__ bta,
                                                     float* __restrict__ y) {
    int row = blockIdx.x;
    const float* xar = xa + (size_t)row * D;
    const float* xbr = xb + (size_t)row * D;
    float* yr = y + (size_t)row * D;
    int t = threadIdx.x;
    float v[3];
#pragma unroll
    for (int j = 0; j < 3; ++j) v[j] = xar[t + j * 256] + xbr[t + j * 256];
    float s = v[0] + v[1] + v[2];
#pragma unroll
    for (int o = 1; o < 64; o <<= 1) s += __shfl_xor(s, o, 64);
    __shared__ float red[4], red2[4];
    int wid = t >> 6;
    if ((t & 63) == 0) red[wid] = s;
    __syncthreads();
    float mean = (red[0] + red[1] + red[2] + red[3]) * (1.0f / 768.0f);
    float d0 = v[0] - mean, d1 = v[1] - mean, d2 = v[2] - mean;
    float sq = d0 * d0 + d1 * d1 + d2 * d2;
#pragma unroll
    for (int o = 1; o < 64; o <<= 1) sq += __shfl_xor(sq, o, 64);
    if ((t & 63) == 0) red2[wid] = sq;
    __syncthreads();
    float var = (red2[0] + red2[1] + red2[2] + red2[3]) * (1.0f / 768.0f);
    float rstd = rsqrtf(var + 1e-5f);
#pragma unroll
    for (int j = 0; j < 3; ++j) {
        int c = t + j * 256;
        yr[c] = (v[j] - mean) * rstd * g[c] + bta[c];
    }
}

// ---------------- prep: qkv weights fp32 -> fp16 --------------------------
__global__ __launch_bounds__(256) void prep_qkv(const float* __restrict__ wq,
                                                const float* __restrict__ wk,
                                                const float* __restrict__ wv,
                                                _Float16* __restrict__ Wh) {
    int idx = blockIdx.x * 256 + threadIdx.x;
    const int per = D * D;
    if (idx >= 3 * per) return;
    int z = idx / per, rem = idx - z * per;
    const float* w = (z == 0) ? wq : (z == 1) ? wk : wv;
    Wh[idx] = (_Float16)w[rem];
}

// ---------------- prep: KAN weights fused+padded fp16 ---------------------
__global__ __launch_bounds__(256) void prep_w(const float* __restrict__ bw,
                                              const float* __restrict__ sw,
                                              const float* __restrict__ scal,
                                              _Float16* __restrict__ Wp, int total) {
    int idx = blockIdx.x * 256 + threadIdx.x;
    if (idx >= total) return;
    float bwv = bw[idx];
    float sc  = scal[idx];
    float4 s0 = *(const float4*)(sw + (size_t)idx * 8);
    float4 s1 = *(const float4*)(sw + (size_t)idx * 8 + 4);
    _Float16* dst = Wp + (size_t)idx * FEAT;
    half2t p0 = {(_Float16)bwv,         (_Float16)(s0.x * sc)};
    half2t p1 = {(_Float16)(s0.y * sc), (_Float16)(s0.z * sc)};
    half2t p2 = {(_Float16)(s0.w * sc), (_Float16)(s1.x * sc)};
    half2t p3 = {(_Float16)(s1.y * sc), (_Float16)(s1.z * sc)};
    half2t p4 = {(_Float16)(s1.w * sc), (_Float16)0.0f};
    *(half2t*)(dst + 0) = p0;
    *(half2t*)(dst + 2) = p1;
    *(half2t*)(dst + 4) = p2;
    *(half2t*)(dst + 6) = p3;
    *(half2t*)(dst + 8) = p4;
}

// ---------------- QKV via fp16 MFMA, writes (B,H,S,DK) fp32 ---------------
// 128x128 tile, 4 waves x (64x64), K-step = 64 halves, A in LDS, B from global.
__global__ __launch_bounds__(256, 2) void qkv16(const _Float16* __restrict__ Xh,
                                                const _Float16* __restrict__ Wh,
                                                const float* __restrict__ bq,
                                                const float* __restrict__ bk,
                                                const float* __restrict__ bv,
                                                float* __restrict__ q,
                                                float* __restrict__ k,
                                                float* __restrict__ v) {
    int z = blockIdx.z;
    const _Float16* W = Wh + (size_t)z * D * D;
    const float* bias = (z == 0) ? bq : (z == 1) ? bk : bv;
    float* out        = (z == 0) ? q  : (z == 1) ? k  : v;

    __shared__ __align__(16) _Float16 As[128][72];
    int t = threadIdx.x;
    int l = t & 63, w = t >> 6;
    int m0 = blockIdx.y * 128, o0 = blockIdx.x * 128;
    int wr = (w >> 1) * 64, wc = (w & 1) * 64;
    int lm = l & 15, lk = (l >> 4) * 8;
    int srow = t >> 1, sh = t & 1;

    f32x4 acc[4][4];
#pragma unroll
    for (int a = 0; a < 4; ++a)
#pragma unroll
        for (int b = 0; b < 4; ++b)
#pragma unroll
            for (int c = 0; c < 4; ++c) acc[a][b][c] = 0.0f;

    const _Float16* bp0 = W + (size_t)(o0 + wc + lm) * D + lk;

    for (int kt = 0; kt < D / 64; ++kt) {
        // stage A tile (pure fp16 copy): 32 halves per thread
        half8 ar[4];
#pragma unroll
        for (int i = 0; i < 4; ++i)
            ar[i] = *(const half8*)(Xh + (size_t)(m0 + srow) * D + kt * 64 + sh * 32 + i * 8);
        __syncthreads();
#pragma unroll
        for (int i = 0; i < 4; ++i)
            *(half8*)&As[srow][sh * 32 + i * 8] = ar[i];
        __syncthreads();
        // issue all B loads for this step (8 frags: 2 kc x 4 nf)
        half8 bfr[2][4];
#pragma unroll
        for (int kc = 0; kc < 2; ++kc)
#pragma unroll
            for (int nf = 0; nf < 4; ++nf)
                bfr[kc][nf] = *(const half8*)(bp0 + (size_t)nf * 16 * D + kt * 64 + kc * 32);
#pragma unroll
        for (int kc = 0; kc < 2; ++kc) {
            half8 a_[4];
#pragma unroll
            for (int mf = 0; mf < 4; ++mf)
                a_[mf] = *(const half8*)&As[wr + mf * 16 + lm][kc * 32 + lk];
#pragma unroll
            for (int mf = 0; mf < 4; ++mf)
#pragma unroll
                for (int nf = 0; nf < 4; ++nf)
                    acc[mf][nf] = __builtin_amdgcn_mfma_f32_16x16x32_f16(a_[mf], bfr[kc][nf], acc[mf][nf], 0, 0, 0);
        }
    }
    int r0 = m0 + wr + (l >> 4) * 4;
    int c0 = o0 + wc + lm;
#pragma unroll
    for (int mf = 0; mf < 4; ++mf)
#pragma unroll
        for (int nf = 0; nf < 4; ++nf) {
            int col = c0 + nf * 16;
            int hh = col >> 6, dd = col & 63;
            float bv_ = bias[col];
#pragma unroll
            for (int r = 0; r < 4; ++r) {
                int n = r0 + mf * 16 + r;
                int b = n >> 11, ss = n & 2047;
                out[(((size_t)(b * Hh + hh) * S + ss) * DK + dd)] = acc[mf][nf][r] + bv_;
            }
        }
}

// ---------------- Flash attention (fp32) ----------------------------------
__global__ __launch_bounds__(256) void attn_kernel(const float* __restrict__ q,
                                                   const float* __restrict__ kg,
                                                   const float* __restrict__ vg,
                                                   float* __restrict__ outp) {
    int bh = blockIdx.y;
    int q0 = blockIdx.x * 64;
    int t = threadIdx.x;
    int r = t >> 2, dg = t & 3;

    __shared__ float Qs[64][65];
    __shared__ float KsT[64][64];
    __shared__ float Vs[64][64];
    __shared__ float Ps[64][65];

    const float* qb = q + ((size_t)bh * S + q0) * DK;
    const float* kb = kg + (size_t)bh * S * DK;
    const float* vb = vg + (size_t)bh * S * DK;

#pragma unroll
    for (int c4 = 0; c4 < 4; ++c4) {
        float4 f = *(const float4*)(qb + r * DK + dg * 16 + c4 * 4);
        Qs[r][dg * 16 + c4 * 4 + 0] = f.x;
        Qs[r][dg * 16 + c4 * 4 + 1] = f.y;
        Qs[r][dg * 16 + c4 * 4 + 2] = f.z;
        Qs[r][dg * 16 + c4 * 4 + 3] = f.w;
    }

    float acc[16];
#pragma unroll
    for (int j = 0; j < 16; ++j) acc[j] = 0.0f;
    float mrow = -INFINITY, lrow = 0.0f;

    for (int kt = 0; kt < S / 64; ++kt) {
        __syncthreads();
#pragma unroll
        for (int c4 = 0; c4 < 4; ++c4) {
            float4 f = *(const float4*)(kb + ((size_t)kt * 64 + r) * DK + dg * 16 + c4 * 4);
            KsT[dg * 16 + c4 * 4 + 0][r] = f.x;
            KsT[dg * 16 + c4 * 4 + 1][r] = f.y;
            KsT[dg * 16 + c4 * 4 + 2][r] = f.z;
            KsT[dg * 16 + c4 * 4 + 3][r] = f.w;
            float4 g2 = *(const float4*)(vb + ((size_t)kt * 64 + r) * DK + dg * 16 + c4 * 4);
            *(float4*)&Vs[r][dg * 16 + c4 * 4] = g2;
        }
        __syncthreads();

        float sc[16];
#pragma unroll
        for (int j = 0; j < 16; ++j) sc[j] = 0.0f;
#pragma unroll 8
        for (int d = 0; d < 64; ++d) {
            float qv = Qs[r][d];
#pragma unroll
            for (int j4 = 0; j4 < 4; ++j4) {
                float4 kf = *(const float4*)&KsT[d][dg * 16 + j4 * 4];
                sc[j4 * 4 + 0] = fmaf(qv, kf.x, sc[j4 * 4 + 0]);
                sc[j4 * 4 + 1] = fmaf(qv, kf.y, sc[j4 * 4 + 1]);
                sc[j4 * 4 + 2] = fmaf(qv, kf.z, sc[j4 * 4 + 2]);
                sc[j4 * 4 + 3] = fmaf(qv, kf.w, sc[j4 * 4 + 3]);
            }
        }
        float pmax = -INFINITY;
#pragma unroll
        for (int j = 0; j < 16; ++j) {
            sc[j] *= 0.125f;
            pmax = fmaxf(pmax, sc[j]);
        }
        pmax = fmaxf(pmax, __shfl_xor(pmax, 1, 64));
        pmax = fmaxf(pmax, __shfl_xor(pmax, 2, 64));
        float mnew = fmaxf(mrow, pmax);
        float corr = __expf(mrow - mnew);
        float p[16];
        float rs = 0.0f;
#pragma unroll
        for (int j = 0; j < 16; ++j) {
            p[j] = __expf(sc[j] - mnew);
            rs += p[j];
        }
        rs += __shfl_xor(rs, 1, 64);
        rs += __shfl_xor(rs, 2, 64);
        lrow = lrow * corr + rs;
        mrow = mnew;
#pragma unroll
        for (int j = 0; j < 16; ++j) acc[j] *= corr;
#pragma unroll
        for (int j = 0; j < 16; ++j) Ps[r][dg * 16 + j] = p[j];
        __syncthreads();
#pragma unroll 8
        for (int kk = 0; kk < 64; ++kk) {
            float pv = Ps[r][kk];
#pragma unroll
            for (int j4 = 0; j4 < 4; ++j4) {
                float4 vf = *(const float4*)&Vs[kk][dg * 16 + j4 * 4];
                acc[j4 * 4 + 0] = fmaf(pv, vf.x, acc[j4 * 4 + 0]);
                acc[j4 * 4 + 1] = fmaf(pv, vf.y, acc[j4 * 4 + 1]);
                acc[j4 * 4 + 2] = fmaf(pv, vf.z, acc[j4 * 4 + 2]);
                acc[j4 * 4 + 3] = fmaf(pv, vf.w, acc[j4 * 4 + 3]);
            }
        }
    }
    float inv = 1.0f / lrow;
    int b = bh / Hh, hh = bh % Hh;
    float* orow = outp + ((size_t)b * S + q0 + r) * D + hh * DK + dg * 16;
#pragma unroll
    for (int c4 = 0; c4 < 4; ++c4) {
        float4 rv;
        rv.x = acc[c4 * 4 + 0] * inv;
        rv.y = acc[c4 * 4 + 1] * inv;
        rv.z = acc[c4 * 4 + 2] * inv;
        rv.w = acc[c4 * 4 + 3] * inv;
        *(float4*)(orow + c4 * 4) = rv;
    }
}

// ------- feature eval: silu + 8 cubic B-spline bases (static-indexed) -----
DEV void features10(float xv, float* f) {
    f[0] = xv / (1.0f + __expf(-xv));
    float sp = (xv + 2.2f) * 2.5f;
    float fj = floorf(sp);
    int j = (int)fj;
    float u = sp - fj;
    float u2 = u * u, u3 = u2 * u;
    float omu = 1.0f - u;
    float b0 = (1.0f / 6.0f) * omu * omu * omu;
    float b1 = 0.5f * u3 - u2 + (2.0f / 3.0f);
    float b2 = -0.5f * u3 + 0.5f * u2 + 0.5f * u + (1.0f / 6.0f);
    float b3 = (1.0f / 6.0f) * u3;
#pragma unroll
    for (int m = 0; m < 8; ++m) {
        int d = j - m;
        f[1 + m] = (d == 3) ? b0 : (d == 2) ? b1 : (d == 1) ? b2 : (d == 0) ? b3 : 0.0f;
    }
    f[9] = 0.0f;
}

// ---------------- KAN GEMM: A-features in LDS, B streamed from global -----
// 128x128 block, 4 waves x (64x64), K-step = 16 inputs = 160 halves.
// NS = 48 K-steps (768 inputs) per block; split-K via blockIdx.z when SPLITK.
template <int IN, typename InT, bool SPLITK>
__global__ __launch_bounds__(256, 2) void kan_mfma(const InT* __restrict__ X,
                                                   const _Float16* __restrict__ Wp,
                                                   _Float16* __restrict__ out16,
                                                   float* __restrict__ out32, int O) {
    constexpr int NS = 48;
    __shared__ __align__(16) _Float16 As[128][LDF];
    int t = threadIdx.x;
    int l = t & 63, w = t >> 6;
    int m0 = blockIdx.y * 128, o0 = blockIdx.x * 128;
    int in0 = SPLITK ? blockIdx.z * 768 : 0;
    int wr = (w >> 1) * 64, wc = (w & 1) * 64;
    int lm = l & 15, lk = (l >> 4) * 8;
    int srow = t >> 1, sh = t & 1;

    const InT* xrow = X + (size_t)(m0 + srow) * IN + in0 + sh * 8;
    const _Float16* bp0 = Wp + (size_t)(o0 + wc + lm) * ((size_t)IN * FEAT)
                        + (size_t)in0 * FEAT + lk;

    f32x4 acc[4][4];
#pragma unroll
    for (int a = 0; a < 4; ++a)
#pragma unroll
        for (int b = 0; b < 4; ++b)
#pragma unroll
            for (int c = 0; c < 4; ++c) acc[a][b][c] = 0.0f;

    // preload x for kt=0
    float xr[8];
    if constexpr (sizeof(InT) == 4) {
        float4 xa = *(const float4*)(xrow);
        float4 xb = *(const float4*)(xrow + 4);
        xr[0]=xa.x; xr[1]=xa.y; xr[2]=xa.z; xr[3]=xa.w;
        xr[4]=xb.x; xr[5]=xb.y; xr[6]=xb.z; xr[7]=xb.w;
    } else {
        half8 xh = *(const half8*)(xrow);
#pragma unroll
        for (int j = 0; j < 8; ++j) xr[j] = (float)xh[j];
    }

    for (int kt = 0; kt < NS; ++kt) {
        // compute 10 features x 8 inputs -> 10 packed half8
        half8 fh[10];
#pragma unroll
        for (int j = 0; j < 8; ++j) {
            float ft[10];
            features10(xr[j], ft);
#pragma unroll
            for (int c = 0; c < 10; ++c) {
                int pos = j * 10 + c;
                fh[pos >> 3][pos & 7] = (_Float16)ft[c];
            }
        }
        __syncthreads();                 // previous MFMA phase done
#pragma unroll
        for (int c = 0; c < 10; ++c)
            *(half8*)&As[srow][sh * 80 + c * 8] = fh[c];
        __syncthreads();
        // prefetch next x (overlaps MFMA phase)
        if (kt + 1 < NS) {
            const InT* xp = xrow + (size_t)(kt + 1) * IK;
            if constexpr (sizeof(InT) == 4) {
                float4 xa = *(const float4*)(xp);
                float4 xb = *(const float4*)(xp + 4);
                xr[0]=xa.x; xr[1]=xa.y; xr[2]=xa.z; xr[3]=xa.w;
                xr[4]=xb.x; xr[5]=xb.y; xr[6]=xb.z; xr[7]=xb.w;
            } else {
                half8 xh = *(const half8*)(xp);
#pragma unroll
                for (int j = 0; j < 8; ++j) xr[j] = (float)xh[j];
            }
        }
        // issue all B loads for this K-step (20 frags)
        half8 bfr[5][4];
        size_t kb = (size_t)kt * BKH;
#pragma unroll
        for (int kc = 0; kc < 5; ++kc)
#pragma unroll
            for (int nf = 0; nf < 4; ++nf)
                bfr[kc][nf] = *(const half8*)(bp0 + (size_t)nf * 16 * IN * FEAT + kb + kc * 32);
#pragma unroll
        for (int kc = 0; kc < 5; ++kc) {
            half8 a_[4];
#pragma unroll
            for (int mf = 0; mf < 4; ++mf)
                a_[mf] = *(const half8*)&As[wr + mf * 16 + lm][kc * 32 + lk];
#pragma unroll
            for (int mf = 0; mf < 4; ++mf)
#pragma unroll
                for (int nf = 0; nf < 4; ++nf)
                    acc[mf][nf] = __builtin_amdgcn_mfma_f32_16x16x32_f16(a_[mf], bfr[kc][nf], acc[mf][nf], 0, 0, 0);
        }
    }
    // epilogue: C map col=lane&15, row=(lane>>4)*4+reg (validated round 3)
    int r0 = m0 + wr + (l >> 4) * 4;
    int c0 = o0 + wc + lm;
#pragma unroll
    for (int mf = 0; mf < 4; ++mf)
#pragma unroll
        for (int nf = 0; nf < 4; ++nf)
#pragma unroll
            for (int r = 0; r < 4; ++r) {
                int row = r0 + mf * 16 + r;
                int col = c0 + nf * 16;
                if constexpr (!SPLITK) {
                    out16[(size_t)row * O + col] = (_Float16)acc[mf][nf][r];
                } else {
                    out32[((size_t)blockIdx.z * Nn + row) * O + col] = acc[mf][nf][r];
                }
            }
}

// ---------------- final reduce: 4 partials + x + attn ---------------------
__global__ __launch_bounds__(256) void reduce4(const float* __restrict__ part,
                                               const float* __restrict__ x,
                                               const float* __restrict__ attno,
                                               float* __restrict__ out) {
    int i = blockIdx.x * 256 + threadIdx.x;
    const size_t ND4 = (size_t)Nn * D / 4;
    if (i >= (int)ND4) return;
    const float4* p0 = (const float4*)part;
    const float4* p1 = p0 + ND4;
    const float4* p2 = p1 + ND4;
    const float4* p3 = p2 + ND4;
    float4 a = p0[i], b = p1[i], c = p2[i], d = p3[i];
    float4 xe = ((const float4*)x)[i], at = ((const float4*)attno)[i];
    float4 o;
    o.x = a.x + b.x + c.x + d.x + xe.x + at.x;
    o.y = a.y + b.y + c.y + d.y + xe.y + at.y;
    o.z = a.z + b.z + c.z + d.z + xe.z + at.z;
    o.w = a.w + b.w + c.w + d.w + xe.w + at.w;
    ((float4*)out)[i] = o;
}

// ---------------- launcher -------------------------------------------------
extern "C" void kernel_launch(void* const* d_in, const int* in_sizes, int n_in,
                              void* d_out, int out_size, void* d_ws, size_t ws_size,
                              hipStream_t stream) {
    const float* x    = (const float*)d_in[0];
    const float* ln1g = (const float*)d_in[2];
    const float* ln1b = (const float*)d_in[3];
    const float* wq   = (const float*)d_in[4];
    const float* bq   = (const float*)d_in[5];
    const float* wk   = (const float*)d_in[6];
    const float* bk   = (const float*)d_in[7];
    const float* wv   = (const float*)d_in[8];
    const float* bv   = (const float*)d_in[9];
    const float* ln2g = (const float*)d_in[10];
    const float* ln2b = (const float*)d_in[11];
    const float* bw1  = (const float*)d_in[12];
    const float* sw1  = (const float*)d_in[13];
    const float* sc1  = (const float*)d_in[14];
    const float* bw2  = (const float*)d_in[15];
    const float* sw2  = (const float*)d_in[16];
    const float* sc2  = (const float*)d_in[17];

    float* ws = (float*)d_ws;
    const size_t ND = (size_t)Nn * D;
    // layout (floats): [xnh ND/2][q ND][k ND][v ND][h ND][attno ND][h1h NF/2][Wp FD*10/2][Wh 3DD/2]
    _Float16* xnh = (_Float16*)ws;
    float* q     = ws + ND / 2;
    float* k     = q + ND;
    float* v     = k + ND;
    float* h     = v + ND;
    float* attno = h + ND;
    _Float16* h1h = (_Float16*)(attno + ND);
    _Float16* Wp  = h1h + (size_t)Nn * F;
    _Float16* Wh  = Wp + (size_t)F * D * FEAT;
    float* part   = q;   // alias q..h (4*ND contiguous), dead by KAN layer 2

    // 1. LN1 -> fp16
    ln16_kernel<<<Nn, 256, 0, stream>>>(x, ln1g, ln1b, xnh);
    // 2. qkv weights fp16
    prep_qkv<<<(3 * D * D + 255) / 256, 256, 0, stream>>>(wq, wk, wv, Wh);
    // 3. QKV MFMA
    qkv16<<<dim3(D / 128, Nn / 128, 3), 256, 0, stream>>>(xnh, Wh, bq, bk, bv, q, k, v);
    // 4. attention (fp32) -> attno
    attn_kernel<<<dim3(S / 64, 2 * Hh), 256, 0, stream>>>(q, k, v, attno);
    // 5. LN2 of (x + attn) -> h
    ln_sum_kernel<<<Nn, 256, 0, stream>>>(x, attno, ln2g, ln2b, h);
    // 6. KAN layer 1 weights, then GEMM 768 -> 3072 (fp16 out)
    prep_w<<<(F * D + 255) / 256, 256, 0, stream>>>(bw1, sw1, sc1, Wp, F * D);
    kan_mfma<768, float, false>
        <<<dim3(F / 128, Nn / 128), 256, 0, stream>>>(h, Wp, h1h, nullptr, F);
    // 7. KAN layer 2 weights, then split-K GEMM 3072 -> 768 (fp32 partials)
    prep_w<<<(D * F + 255) / 256, 256, 0, stream>>>(bw2, sw2, sc2, Wp, D * F);
    kan_mfma<3072, _Float16, true>
        <<<dim3(D / 128, Nn / 128, 4), 256, 0, stream>>>(h1h, Wp, nullptr, part, D);
    // 8. reduce partials + residuals -> out
    reduce4<<<(int)(ND / 4 / 256), 256, 0, stream>>>(part, x, attno, (float*)d_out);
}

// Round 5
// 1133.075 us; speedup vs baseline: 5.1244x; 1.9658x over previous
//
#include <hip/hip_runtime.h>
#include <hip/hip_fp16.h>
#include <math.h>

#define DEV static __device__ __forceinline__

namespace {
constexpr int S  = 2048;
constexpr int D  = 768;
constexpr int Hh = 12;
constexpr int DK = 64;
constexpr int F  = 3072;
constexpr int Nn = 4096;
constexpr int FEAT = 9;            // 1 silu + 8 spline (no pad)
constexpr int K1   = D * FEAT;     // 6912 (= L2 chunk K as well)
constexpr int LDAB = 6912;         // row stride of feat / packed W (elements)
}

typedef _Float16 half8 __attribute__((ext_vector_type(8)));
typedef float f32x4 __attribute__((ext_vector_type(4)));

// global -> LDS direct copy, 16B per lane, LDS dest = wave-uniform base + lane*16
DEV void gld16(const void* g, void* l) {
    __builtin_amdgcn_global_load_lds((__attribute__((address_space(1))) void*)g,
                                     (__attribute__((address_space(3))) void*)l,
                                     16, 0, 0);
}

// ------- feature eval: silu + 8 cubic B-spline bases (validated r2-r4) ----
DEV void features9(float xv, float* f) {
    f[0] = xv / (1.0f + __expf(-xv));
    float sp = (xv + 2.2f) * 2.5f;
    float fj = floorf(sp);
    int j = (int)fj;
    float u = sp - fj;
    float u2 = u * u, u3 = u2 * u;
    float omu = 1.0f - u;
    float b0 = (1.0f / 6.0f) * omu * omu * omu;
    float b1 = 0.5f * u3 - u2 + (2.0f / 3.0f);
    float b2 = -0.5f * u3 + 0.5f * u2 + 0.5f * u + (1.0f / 6.0f);
    float b3 = (1.0f / 6.0f) * u3;
#pragma unroll
    for (int m = 0; m < 8; ++m) {
        int d = j - m;
        f[1 + m] = (d == 3) ? b0 : (d == 2) ? b1 : (d == 1) ? b2 : (d == 0) ? b3 : 0.0f;
    }
}

// ---------------- LN1: fp32 in -> fp16 out --------------------------------
__global__ __launch_bounds__(256) void ln16_kernel(const float* __restrict__ x,
                                                   const float* __restrict__ g,
                                                   const float* __restrict__ bta,
                                                   _Float16* __restrict__ y) {
    int row = blockIdx.x;
    const float* xr = x + (size_t)row * D;
    _Float16* yr = y + (size_t)row * D;
    int t = threadIdx.x;
    float v[3];
#pragma unroll
    for (int j = 0; j < 3; ++j) v[j] = xr[t + j * 256];
    float s = v[0] + v[1] + v[2];
#pragma unroll
    for (int o = 1; o < 64; o <<= 1) s += __shfl_xor(s, o, 64);
    __shared__ float red[4], red2[4];
    int wid = t >> 6;
    if ((t & 63) == 0) red[wid] = s;
    __syncthreads();
    float mean = (red[0] + red[1] + red[2] + red[3]) * (1.0f / 768.0f);
    float d0 = v[0] - mean, d1 = v[1] - mean, d2 = v[2] - mean;
    float sq = d0 * d0 + d1 * d1 + d2 * d2;
#pragma unroll
    for (int o = 1; o < 64; o <<= 1) sq += __shfl_xor(sq, o, 64);
    if ((t & 63) == 0) red2[wid] = sq;
    __syncthreads();
    float var = (red2[0] + red2[1] + red2[2] + red2[3]) * (1.0f / 768.0f);
    float rstd = rsqrtf(var + 1e-5f);
#pragma unroll
    for (int j = 0; j < 3; ++j) {
        int c = t + j * 256;
        yr[c] = (_Float16)((v[j] - mean) * rstd * g[c] + bta[c]);
    }
}

// ------- LN2 of (x + attn) fused with feature expansion -> feat1 ----------
__global__ __launch_bounds__(256) void ln_feat(const float* __restrict__ xa,
                                               const float* __restrict__ xb,
                                               const float* __restrict__ g,
                                               const float* __restrict__ bta,
                                               _Float16* __restrict__ feat) {
    int row = blockIdx.x;
    const float* xar = xa + (size_t)row * D;
    const float* xbr = xb + (size_t)row * D;
    int t = threadIdx.x;
    float v[3];
#pragma unroll
    for (int j = 0; j < 3; ++j) v[j] = xar[t + j * 256] + xbr[t + j * 256];
    float s = v[0] + v[1] + v[2];
#pragma unroll
    for (int o = 1; o < 64; o <<= 1) s += __shfl_xor(s, o, 64);
    __shared__ float red[4], red2[4];
    __shared__ __align__(16) _Float16 fbuf[K1];
    int wid = t >> 6;
    if ((t & 63) == 0) red[wid] = s;
    __syncthreads();
    float mean = (red[0] + red[1] + red[2] + red[3]) * (1.0f / 768.0f);
    float d0 = v[0] - mean, d1 = v[1] - mean, d2 = v[2] - mean;
    float sq = d0 * d0 + d1 * d1 + d2 * d2;
#pragma unroll
    for (int o = 1; o < 64; o <<= 1) sq += __shfl_xor(sq, o, 64);
    if ((t & 63) == 0) red2[wid] = sq;
    __syncthreads();
    float var = (red2[0] + red2[1] + red2[2] + red2[3]) * (1.0f / 768.0f);
    float rstd = rsqrtf(var + 1e-5f);
#pragma unroll
    for (int j = 0; j < 3; ++j) {
        int c = t + j * 256;
        float y = (v[j] - mean) * rstd * g[c] + bta[c];
        float f[9];
        features9(y, f);
#pragma unroll
        for (int cc = 0; cc < 9; ++cc) fbuf[c * 9 + cc] = (_Float16)f[cc];
    }
    __syncthreads();
    _Float16* dst = feat + (size_t)row * K1;
    for (int i = t; i < K1 / 8; i += 256)
        *(half8*)(dst + i * 8) = *(const half8*)&fbuf[i * 8];
}

// ------- feature expansion of h1 chunk (768 cols) -> featbuf --------------
__global__ __launch_bounds__(256) void feat2_chunk(const _Float16* __restrict__ h1,
                                                   int c0,
                                                   _Float16* __restrict__ feat) {
    int row = blockIdx.x;
    int t = threadIdx.x;
    __shared__ __align__(16) _Float16 fbuf[K1];
    const _Float16* src = h1 + (size_t)row * F + c0;
#pragma unroll
    for (int j = 0; j < 3; ++j) {
        int ic = t + j * 256;
        float y = (float)src[ic];
        float f[9];
        features9(y, f);
#pragma unroll
        for (int cc = 0; cc < 9; ++cc) fbuf[ic * 9 + cc] = (_Float16)f[cc];
    }
    __syncthreads();
    _Float16* dst = feat + (size_t)row * K1;
    for (int i = t; i < K1 / 8; i += 256)
        *(half8*)(dst + i * 8) = *(const half8*)&fbuf[i * 8];
}

// ------- pack KAN weights: Wp[o][ic*9+c] = {base_w, spline*scaler} fp16 ---
// grid (3, O); handles 768 input-cols starting at c0 of a row-major (O,INfull) set
__global__ __launch_bounds__(256) void prep_w(const float* __restrict__ bw,
                                              const float* __restrict__ sw,
                                              const float* __restrict__ scal,
                                              _Float16* __restrict__ Wp,
                                              int INfull, int c0) {
    int o = blockIdx.y;
    int ic = blockIdx.x * 256 + threadIdx.x;
    size_t idx = (size_t)o * INfull + c0 + ic;
    float bwv = bw[idx];
    float sc  = scal[idx];
    float4 s0 = *(const float4*)(sw + idx * 8);
    float4 s1 = *(const float4*)(sw + idx * 8 + 4);
    _Float16* dst = Wp + ((size_t)o * 768 + ic) * 9;
    dst[0] = (_Float16)bwv;
    dst[1] = (_Float16)(s0.x * sc);
    dst[2] = (_Float16)(s0.y * sc);
    dst[3] = (_Float16)(s0.z * sc);
    dst[4] = (_Float16)(s0.w * sc);
    dst[5] = (_Float16)(s1.x * sc);
    dst[6] = (_Float16)(s1.y * sc);
    dst[7] = (_Float16)(s1.z * sc);
    dst[8] = (_Float16)(s1.w * sc);
}

// ---------------- prep: qkv weights fp32 -> fp16 --------------------------
__global__ __launch_bounds__(256) void prep_qkv(const float* __restrict__ wq,
                                                const float* __restrict__ wk,
                                                const float* __restrict__ wv,
                                                _Float16* __restrict__ Wh) {
    int idx = blockIdx.x * 256 + threadIdx.x;
    const int per = D * D;
    if (idx >= 3 * per) return;
    int z = idx / per, rem = idx - z * per;
    const float* w = (z == 0) ? wq : (z == 1) ? wk : wv;
    Wh[idx] = (_Float16)w[rem];
}

// ---------------- QKV via fp16 MFMA, writes (B,H,S,DK) fp16 ---------------
__global__ __launch_bounds__(256, 2) void qkv16(const _Float16* __restrict__ Xh,
                                                const _Float16* __restrict__ Wh,
                                                const float* __restrict__ bq,
                                                const float* __restrict__ bk,
                                                const float* __restrict__ bv,
                                                _Float16* __restrict__ q,
                                                _Float16* __restrict__ k,
                                                _Float16* __restrict__ v) {
    int z = blockIdx.z;
    const _Float16* W = Wh + (size_t)z * D * D;
    const float* bias = (z == 0) ? bq : (z == 1) ? bk : bv;
    _Float16* out     = (z == 0) ? q  : (z == 1) ? k  : v;

    __shared__ __align__(16) _Float16 As[128][72];
    int t = threadIdx.x;
    int l = t & 63, w = t >> 6;
    int m0 = blockIdx.y * 128, o0 = blockIdx.x * 128;
    int wr = (w >> 1) * 64, wc = (w & 1) * 64;
    int lm = l & 15, lk = (l >> 4) * 8;
    int srow = t >> 1, sh = t & 1;

    f32x4 acc[4][4];
#pragma unroll
    for (int a = 0; a < 4; ++a)
#pragma unroll
        for (int b = 0; b < 4; ++b)
#pragma unroll
            for (int c = 0; c < 4; ++c) acc[a][b][c] = 0.0f;

    const _Float16* bp0 = W + (size_t)(o0 + wc + lm) * D + lk;

    for (int kt = 0; kt < D / 64; ++kt) {
        half8 ar[4];
#pragma unroll
        for (int i = 0; i < 4; ++i)
            ar[i] = *(const half8*)(Xh + (size_t)(m0 + srow) * D + kt * 64 + sh * 32 + i * 8);
        __syncthreads();
#pragma unroll
        for (int i = 0; i < 4; ++i)
            *(half8*)&As[srow][sh * 32 + i * 8] = ar[i];
        __syncthreads();
        half8 bfr[2][4];
#pragma unroll
        for (int kc = 0; kc < 2; ++kc)
#pragma unroll
            for (int nf = 0; nf < 4; ++nf)
                bfr[kc][nf] = *(const half8*)(bp0 + (size_t)nf * 16 * D + kt * 64 + kc * 32);
#pragma unroll
        for (int kc = 0; kc < 2; ++kc) {
            half8 a_[4];
#pragma unroll
            for (int mf = 0; mf < 4; ++mf)
                a_[mf] = *(const half8*)&As[wr + mf * 16 + lm][kc * 32 + lk];
#pragma unroll
            for (int mf = 0; mf < 4; ++mf)
#pragma unroll
                for (int nf = 0; nf < 4; ++nf)
                    acc[mf][nf] = __builtin_amdgcn_mfma_f32_16x16x32_f16(a_[mf], bfr[kc][nf], acc[mf][nf], 0, 0, 0);
        }
    }
    int r0 = m0 + wr + (l >> 4) * 4;
    int c0 = o0 + wc + lm;
#pragma unroll
    for (int mf = 0; mf < 4; ++mf)
#pragma unroll
        for (int nf = 0; nf < 4; ++nf) {
            int col = c0 + nf * 16;
            int hh = col >> 6, dd = col & 63;
            float bv_ = bias[col];
#pragma unroll
            for (int r = 0; r < 4; ++r) {
                int n = r0 + mf * 16 + r;
                int b = n >> 11, ss = n & 2047;
                out[(((size_t)(b * Hh + hh) * S + ss) * DK + dd)] = (_Float16)(acc[mf][nf][r] + bv_);
            }
        }
}

// ---------------- Flash attention, fp16 MFMA ------------------------------
// 64 q-rows/block, 4 waves x 16 rows; K-tiles of 64 keys.
__global__ __launch_bounds__(256) void attn16(const _Float16* __restrict__ q16,
                                              const _Float16* __restrict__ k16,
                                              const _Float16* __restrict__ v16,
                                              float* __restrict__ attno) {
    int bh = blockIdx.y;
    int q0 = blockIdx.x * 64;
    int t = threadIdx.x;
    int l = t & 63, w = t >> 6;
    int lm = l & 15, lk = (l >> 4) * 8;
    int wr = w * 16;                  // wave's q-row base in tile

    __shared__ __align__(16) _Float16 Qs[64][72];
    __shared__ __align__(16) _Float16 Ks[64][72];
    __shared__ __align__(16) _Float16 Vt[64][72];   // [d][key]
    __shared__ __align__(16) _Float16 Ps[64][72];

    const _Float16* qb = q16 + ((size_t)bh * S + q0) * DK;
    const _Float16* kb = k16 + (size_t)bh * S * DK;
    const _Float16* vb = v16 + (size_t)bh * S * DK;

    {   // stage Q once, fold 1/8 score scale (exact in fp16)
        int row = t & 63, dg = t >> 6;
        half8 h0 = *(const half8*)(qb + row * DK + dg * 16);
        half8 h1 = *(const half8*)(qb + row * DK + dg * 16 + 8);
#pragma unroll
        for (int j = 0; j < 8; ++j) { h0[j] = h0[j] * (_Float16)0.125f; h1[j] = h1[j] * (_Float16)0.125f; }
        *(half8*)&Qs[row][dg * 16] = h0;
        *(half8*)&Qs[row][dg * 16 + 8] = h1;
    }

    float m_[4], l_[4];
    f32x4 oacc[4];
#pragma unroll
    for (int r = 0; r < 4; ++r) { m_[r] = -INFINITY; l_[r] = 0.0f; }
#pragma unroll
    for (int nf = 0; nf < 4; ++nf)
#pragma unroll
        for (int r = 0; r < 4; ++r) oacc[nf][r] = 0.0f;

    for (int kt = 0; kt < S / 64; ++kt) {
        __syncthreads();   // prev tile fully consumed (also covers Q stage at kt=0)
        {
            int key = t & 63, dg = t >> 6;
            const _Float16* kr = kb + ((size_t)kt * 64 + key) * DK + dg * 16;
            half8 k0 = *(const half8*)(kr);
            half8 k1 = *(const half8*)(kr + 8);
            *(half8*)&Ks[key][dg * 16] = k0;
            *(half8*)&Ks[key][dg * 16 + 8] = k1;
            const _Float16* vr = vb + ((size_t)kt * 64 + key) * DK + dg * 16;
            half8 v0 = *(const half8*)(vr);
            half8 v1 = *(const half8*)(vr + 8);
#pragma unroll
            for (int j = 0; j < 8; ++j) {
                Vt[dg * 16 + j][key] = v0[j];
                Vt[dg * 16 + 8 + j][key] = v1[j];
            }
        }
        __syncthreads();

        // S = Q K^T (scaled), wave's 16 rows x 64 keys
        f32x4 sc[4];
#pragma unroll
        for (int nf = 0; nf < 4; ++nf)
#pragma unroll
            for (int r = 0; r < 4; ++r) sc[nf][r] = 0.0f;
#pragma unroll
        for (int kc = 0; kc < 2; ++kc) {
            half8 aq = *(const half8*)&Qs[wr + lm][kc * 32 + lk];
#pragma unroll
            for (int nf = 0; nf < 4; ++nf) {
                half8 bk8 = *(const half8*)&Ks[nf * 16 + lm][kc * 32 + lk];
                sc[nf] = __builtin_amdgcn_mfma_f32_16x16x32_f16(aq, bk8, sc[nf], 0, 0, 0);
            }
        }
        // online softmax; lane's rows: wr + (l>>4)*4 + r
        float pmax[4];
#pragma unroll
        for (int r = 0; r < 4; ++r) {
            pmax[r] = fmaxf(fmaxf(sc[0][r], sc[1][r]), fmaxf(sc[2][r], sc[3][r]));
#pragma unroll
            for (int mk = 1; mk < 16; mk <<= 1)
                pmax[r] = fmaxf(pmax[r], __shfl_xor(pmax[r], mk, 64));
        }
        float corr[4], rs[4];
#pragma unroll
        for (int r = 0; r < 4; ++r) {
            float mnew = fmaxf(m_[r], pmax[r]);
            corr[r] = __expf(m_[r] - mnew);
            m_[r] = mnew;
            rs[r] = 0.0f;
        }
#pragma unroll
        for (int nf = 0; nf < 4; ++nf)
#pragma unroll
            for (int r = 0; r < 4; ++r) {
                float p = __expf(sc[nf][r] - m_[r]);
                sc[nf][r] = p;
                rs[r] += p;
            }
#pragma unroll
        for (int r = 0; r < 4; ++r) {
#pragma unroll
            for (int mk = 1; mk < 16; mk <<= 1)
                rs[r] += __shfl_xor(rs[r], mk, 64);
            l_[r] = l_[r] * corr[r] + rs[r];
        }
        // P -> LDS fp16 (wave-private rows), rescale O
        int pr = wr + (l >> 4) * 4;
#pragma unroll
        for (int nf = 0; nf < 4; ++nf)
#pragma unroll
            for (int r = 0; r < 4; ++r)
                Ps[pr + r][nf * 16 + lm] = (_Float16)sc[nf][r];
#pragma unroll
        for (int nf = 0; nf < 4; ++nf)
#pragma unroll
            for (int r = 0; r < 4; ++r) oacc[nf][r] *= corr[r];
        // O += P V
#pragma unroll
        for (int kc = 0; kc < 2; ++kc) {
            half8 ap = *(const half8*)&Ps[wr + lm][kc * 32 + lk];
#pragma unroll
            for (int nf = 0; nf < 4; ++nf) {
                half8 bv8 = *(const half8*)&Vt[nf * 16 + lm][kc * 32 + lk];
                oacc[nf] = __builtin_amdgcn_mfma_f32_16x16x32_f16(ap, bv8, oacc[nf], 0, 0, 0);
            }
        }
    }
    int b = bh / Hh, hh = bh % Hh;
    int pr = wr + (l >> 4) * 4;
#pragma unroll
    for (int r = 0; r < 4; ++r) {
        float inv = 1.0f / l_[r];
        float* orow = attno + ((size_t)b * S + q0 + pr + r) * D + hh * DK;
#pragma unroll
        for (int nf = 0; nf < 4; ++nf)
            orow[nf * 16 + lm] = oacc[nf][r] * inv;
    }
}

// ---------------- pure fp16 GEMM (m97 structure): C = A * B^T -------------
// A: (M x 6912) fp16 row-major; B: (O x 6912) fp16 row-major.
// 128x128 tile, 4 waves x (64x64), BK=64, global_load_lds staging.
// slot = blockIdx.z: A += slot*KS*64, B += slot*KS*64 (split-K slices).
template <int KS, bool TOF16>
__global__ __launch_bounds__(256) void kan_gemm(const _Float16* __restrict__ A,
                                                const _Float16* __restrict__ B,
                                                _Float16* __restrict__ out16,
                                                float* __restrict__ out32,
                                                int O, int accum) {
    __shared__ __align__(16) _Float16 Al[128 * 64];
    __shared__ __align__(16) _Float16 Bl[128 * 64];
    int t = threadIdx.x;
    int l = t & 63, w = t >> 6;
    int m0 = blockIdx.y * 128, o0 = blockIdx.x * 128;
    int slot = blockIdx.z;
    int wr = (w >> 1) * 64, wc = (w & 1) * 64;
    int lm = l & 15, lk = (l >> 4) * 8;

    const _Float16* Ab = A + (size_t)slot * KS * 64;
    const _Float16* Bb = B + (size_t)slot * KS * 64;
    // per-lane global src for staging: row chunk j covers rows (w*32+j*8 .. +8)
    int srow = l >> 3, scol = (l & 7) * 8;

    f32x4 acc[4][4];
#pragma unroll
    for (int a = 0; a < 4; ++a)
#pragma unroll
        for (int b = 0; b < 4; ++b)
#pragma unroll
            for (int c = 0; c < 4; ++c) acc[a][b][c] = 0.0f;

    for (int kt = 0; kt < KS; ++kt) {
        if (kt) __syncthreads();        // previous iteration's LDS reads done
        size_t kofs = (size_t)kt * 64 + scol;
#pragma unroll
        for (int j = 0; j < 4; ++j) {
            int row = w * 32 + j * 8;
            gld16(Ab + (size_t)(m0 + row + srow) * LDAB + kofs, &Al[row * 64]);
            gld16(Bb + (size_t)(o0 + row + srow) * LDAB + kofs, &Bl[row * 64]);
        }
        __syncthreads();                // compiler drains vmcnt before barrier
#pragma unroll
        for (int kc = 0; kc < 2; ++kc) {
            half8 af[4], bf[4];
#pragma unroll
            for (int mf = 0; mf < 4; ++mf)
                af[mf] = *(const half8*)&Al[(wr + mf * 16 + lm) * 64 + kc * 32 + lk];
#pragma unroll
            for (int nf = 0; nf < 4; ++nf)
                bf[nf] = *(const half8*)&Bl[(wc + nf * 16 + lm) * 64 + kc * 32 + lk];
#pragma unroll
            for (int mf = 0; mf < 4; ++mf)
#pragma unroll
                for (int nf = 0; nf < 4; ++nf)
                    acc[mf][nf] = __builtin_amdgcn_mfma_f32_16x16x32_f16(af[mf], bf[nf], acc[mf][nf], 0, 0, 0);
        }
    }
    int r0 = m0 + wr + (l >> 4) * 4;
    int c0 = o0 + wc + lm;
#pragma unroll
    for (int mf = 0; mf < 4; ++mf)
#pragma unroll
        for (int nf = 0; nf < 4; ++nf)
#pragma unroll
            for (int r = 0; r < 4; ++r) {
                int row = r0 + mf * 16 + r;
                int col = c0 + nf * 16;
                if constexpr (TOF16) {
                    out16[(size_t)row * O + col] = (_Float16)acc[mf][nf][r];
                } else {
                    float* po = out32 + ((size_t)slot * Nn + row) * O + col;
                    float vv = acc[mf][nf][r];
                    if (accum) vv += *po;
                    *po = vv;
                }
            }
}

// ---------------- final reduce: 4 partials + x + attn ---------------------
__global__ __launch_bounds__(256) void reduce4(const float* __restrict__ part,
                                               const float* __restrict__ x,
                                               const float* __restrict__ attno,
                                               float* __restrict__ out) {
    int i = blockIdx.x * 256 + threadIdx.x;
    const size_t ND4 = (size_t)Nn * D / 4;
    if (i >= (int)ND4) return;
    const float4* p0 = (const float4*)part;
    const float4* p1 = p0 + ND4;
    const float4* p2 = p1 + ND4;
    const float4* p3 = p2 + ND4;
    float4 a = p0[i], b = p1[i], c = p2[i], d = p3[i];
    float4 xe = ((const float4*)x)[i], at = ((const float4*)attno)[i];
    float4 o;
    o.x = a.x + b.x + c.x + d.x + xe.x + at.x;
    o.y = a.y + b.y + c.y + d.y + xe.y + at.y;
    o.z = a.z + b.z + c.z + d.z + xe.z + at.z;
    o.w = a.w + b.w + c.w + d.w + xe.w + at.w;
    ((float4*)out)[i] = o;
}

// ---------------- launcher -------------------------------------------------
extern "C" void kernel_launch(void* const* d_in, const int* in_sizes, int n_in,
                              void* d_out, int out_size, void* d_ws, size_t ws_size,
                              hipStream_t stream) {
    const float* x    = (const float*)d_in[0];
    const float* ln1g = (const float*)d_in[2];
    const float* ln1b = (const float*)d_in[3];
    const float* wq   = (const float*)d_in[4];
    const float* bq   = (const float*)d_in[5];
    const float* wk   = (const float*)d_in[6];
    const float* bk   = (const float*)d_in[7];
    const float* wv   = (const float*)d_in[8];
    const float* bv   = (const float*)d_in[9];
    const float* ln2g = (const float*)d_in[10];
    const float* ln2b = (const float*)d_in[11];
    const float* bw1  = (const float*)d_in[12];
    const float* sw1  = (const float*)d_in[13];
    const float* sc1  = (const float*)d_in[14];
    const float* bw2  = (const float*)d_in[15];
    const float* sw2  = (const float*)d_in[16];
    const float* sc2  = (const float*)d_in[17];

    const size_t ND = (size_t)Nn * D;
    char* base = (char*)d_ws;
    // R0: feature buffer 56.6MB (also hosts q16/k16/v16 early)
    _Float16* featbuf = (_Float16*)base;                              // Nn*K1
    _Float16* q16 = featbuf;
    _Float16* k16 = featbuf + ND;
    _Float16* v16 = featbuf + 2 * ND;
    char* p = base + (size_t)Nn * K1 * 2;                             // +56,623,104
    float* attno = (float*)p;            p += ND * 4;                 // 12.58MB
    _Float16* h1h = (_Float16*)p;        p += (size_t)Nn * F * 2;     // 25.17MB
    // R3: 52.3MB region — Wp1 | xnh | Wh early; part later
    char* R3 = p;
    _Float16* Wp1 = (_Float16*)R3;                                    // 42,467,328
    _Float16* xnh = (_Float16*)(R3 + 42467328);                       // 6,291,456
    _Float16* Wh  = (_Float16*)(R3 + 48758784);                       // 3,538,944
    float* part   = (float*)R3;                                       // 4*ND*4 = 50.33MB
    char* R4 = R3 + 52297728;
    _Float16* Wp2c = (_Float16*)R4;                                   // 10.62MB

    // 1. LN1 -> fp16
    ln16_kernel<<<Nn, 256, 0, stream>>>(x, ln1g, ln1b, xnh);
    // 2. qkv weights fp16
    prep_qkv<<<(3 * D * D + 255) / 256, 256, 0, stream>>>(wq, wk, wv, Wh);
    // 3. QKV -> fp16 (B,H,S,DK)
    qkv16<<<dim3(D / 128, Nn / 128, 3), 256, 0, stream>>>(xnh, Wh, bq, bk, bv, q16, k16, v16);
    // 4. flash attention (MFMA) -> attno fp32
    attn16<<<dim3(S / 64, 2 * Hh), 256, 0, stream>>>(q16, k16, v16, attno);
    // 5. pack layer-1 weights (3072 x 768 x 9)
    prep_w<<<dim3(3, F), 256, 0, stream>>>(bw1, sw1, sc1, Wp1, D, 0);
    // 6. LN2(x+attn) + feature expansion -> feat1 (overwrites q/k/v)
    ln_feat<<<Nn, 256, 0, stream>>>(x, attno, ln2g, ln2b, featbuf);
    // 7. KAN layer 1 GEMM: (4096x6912) x (3072x6912)^T -> h1h fp16
    kan_gemm<108, true><<<dim3(F / 128, Nn / 128, 1), 256, 0, stream>>>(
        featbuf, Wp1, h1h, nullptr, F, 0);
    // 8. KAN layer 2 in 4 K-chunks of 768 inputs; split-K z=4 within chunk
    for (int c = 0; c < 4; ++c) {
        prep_w<<<dim3(3, D), 256, 0, stream>>>(bw2, sw2, sc2, Wp2c, F, c * 768);
        feat2_chunk<<<Nn, 256, 0, stream>>>(h1h, c * 768, featbuf);
        kan_gemm<27, false><<<dim3(D / 128, Nn / 128, 4), 256, 0, stream>>>(
            featbuf, Wp2c, nullptr, part, D, c > 0);
    }
    // 9. partials + residuals -> out
    reduce4<<<(int)(ND / 4 / 256), 256, 0, stream>>>(part, x, attno, (float*)d_out);
}